// Round 1
// baseline (1205.610 us; speedup 1.0000x reference)
//
#include <hip/hip_runtime.h>

#define N_NODES 100000
#define N_EDGES 1600000
#define HDIM 128

// ---------------- CSR build ----------------

__global__ void hist_kernel(const int* __restrict__ ei, int* __restrict__ counts, int e) {
  int i = blockIdx.x * blockDim.x + threadIdx.x;
  if (i < e) atomicAdd(&counts[ei[e + i]], 1);  // dst row = ei[E..2E)
}

__global__ void scan1_kernel(const int* __restrict__ counts, int* __restrict__ offs,
                             int* __restrict__ bsums, int n) {
  __shared__ int sd[256];
  int t = threadIdx.x;
  int base = blockIdx.x * 1024 + t * 4;
  int v0 = (base + 0 < n) ? counts[base + 0] : 0;
  int v1 = (base + 1 < n) ? counts[base + 1] : 0;
  int v2 = (base + 2 < n) ? counts[base + 2] : 0;
  int v3 = (base + 3 < n) ? counts[base + 3] : 0;
  int s = v0 + v1 + v2 + v3;
  sd[t] = s;
  __syncthreads();
  for (int off = 1; off < 256; off <<= 1) {
    int x = (t >= off) ? sd[t - off] : 0;
    __syncthreads();
    sd[t] += x;
    __syncthreads();
  }
  int excl = sd[t] - s;
  if (t == 255) bsums[blockIdx.x] = sd[255];
  int r = excl;
  if (base + 0 < n) offs[base + 0] = r; r += v0;
  if (base + 1 < n) offs[base + 1] = r; r += v1;
  if (base + 2 < n) offs[base + 2] = r; r += v2;
  if (base + 3 < n) offs[base + 3] = r;
}

__global__ void scan2_kernel(int* __restrict__ bsums, int nb) {
  __shared__ int sd[128];
  int t = threadIdx.x;
  int v = (t < nb) ? bsums[t] : 0;
  sd[t] = v;
  __syncthreads();
  for (int off = 1; off < 128; off <<= 1) {
    int x = (t >= off) ? sd[t - off] : 0;
    __syncthreads();
    sd[t] += x;
    __syncthreads();
  }
  if (t < nb) bsums[t] = sd[t] - v;  // exclusive
}

__global__ void scan3_kernel(int* __restrict__ offs, const int* __restrict__ bsums, int n) {
  int i = blockIdx.x * blockDim.x + threadIdx.x;
  if (i < n) offs[i] += bsums[i >> 10];
}

__global__ void fill_kernel(const int* __restrict__ ei, const int* __restrict__ offs,
                            int* __restrict__ cursor, int* __restrict__ srcs, int e) {
  int i = blockIdx.x * blockDim.x + threadIdx.x;
  if (i < e) {
    int d = ei[e + i];
    int pos = offs[d] + atomicAdd(&cursor[d], 1);
    srcs[pos] = ei[i];  // src row = ei[0..E)
  }
}

// ---------------- aggregation: z[i] = h[i] + sum_{j in N_in(i)} h[j] ----------------
// one wave (64 lanes) per node, float2 per lane = 128 floats

__global__ void aggregate_kernel(const float* __restrict__ h, const int* __restrict__ offs,
                                 const int* __restrict__ deg, const int* __restrict__ srcs,
                                 float* __restrict__ z, int n) {
  int wid = (int)((blockIdx.x * blockDim.x + threadIdx.x) >> 6);
  int lane = threadIdx.x & 63;
  if (wid >= n) return;
  int beg = offs[wid];
  int d = deg[wid];
  const int col = lane * 2;
  float2 acc = *(const float2*)(h + (size_t)wid * HDIM + col);
  int j = 0;
  for (; j + 4 <= d; j += 4) {
    int s0 = srcs[beg + j + 0];
    int s1 = srcs[beg + j + 1];
    int s2 = srcs[beg + j + 2];
    int s3 = srcs[beg + j + 3];
    float2 a0 = *(const float2*)(h + (size_t)s0 * HDIM + col);
    float2 a1 = *(const float2*)(h + (size_t)s1 * HDIM + col);
    float2 a2 = *(const float2*)(h + (size_t)s2 * HDIM + col);
    float2 a3 = *(const float2*)(h + (size_t)s3 * HDIM + col);
    acc.x += a0.x + a1.x + a2.x + a3.x;
    acc.y += a0.y + a1.y + a2.y + a3.y;
  }
  for (; j < d; ++j) {
    int s = srcs[beg + j];
    float2 a = *(const float2*)(h + (size_t)s * HDIM + col);
    acc.x += a.x;
    acc.y += a.y;
  }
  *(float2*)(z + (size_t)wid * HDIM + col) = acc;
}

// ---------------- fp32 GEMM: out[N,128] = relu(A[N,128] @ W[128,128] + bias) ----------------
// 128x128 tile per 256-thread block; A row-major XOR-swizzled, W transposed XOR-swizzled in LDS.

__global__ __launch_bounds__(256, 1)
void gemm_kernel(const float* __restrict__ A, const float* __restrict__ W,
                 const float* __restrict__ bias, float* __restrict__ out, int n) {
  __shared__ float As[128 * 128];  // As[r*128 + (k ^ (((r>>3)&3)<<2))]
  __shared__ float Ws[128 * 128];  // Wt[c*128 + (k ^ ((c>>3)<<2))]
  int t = threadIdx.x;
  int rowBase = blockIdx.x * 128;

  // stage W (transpose + swizzle); W[k][c] row-major in global
  #pragma unroll
  for (int it = 0; it < 16; ++it) {
    int idx = (it * 256 + t) * 4;
    int k = idx >> 7;
    int c0 = idx & 127;
    float4 v = *(const float4*)(W + idx);
    Ws[(c0 + 0) * 128 + (k ^ (((c0 + 0) >> 3) << 2))] = v.x;
    Ws[(c0 + 1) * 128 + (k ^ (((c0 + 1) >> 3) << 2))] = v.y;
    Ws[(c0 + 2) * 128 + (k ^ (((c0 + 2) >> 3) << 2))] = v.z;
    Ws[(c0 + 3) * 128 + (k ^ (((c0 + 3) >> 3) << 2))] = v.w;
  }
  // stage A (row-major + swizzle)
  #pragma unroll
  for (int it = 0; it < 16; ++it) {
    int idx = (it * 256 + t) * 4;
    int r = idx >> 7;
    int k = idx & 127;
    int gr = rowBase + r;
    float4 v;
    if (gr < n) v = *(const float4*)(A + (size_t)gr * HDIM + k);
    else { v.x = 0.f; v.y = 0.f; v.z = 0.f; v.w = 0.f; }
    *(float4*)&As[r * 128 + (k ^ (((r >> 3) & 3) << 2))] = v;
  }
  __syncthreads();

  int tc = t & 15;   // 16 col groups of 8
  int tr = t >> 4;   // 16 row groups of 8
  float acc[8][8];
  #pragma unroll
  for (int i = 0; i < 8; ++i)
    #pragma unroll
    for (int j = 0; j < 8; ++j) acc[i][j] = 0.f;

  const float* Abase = &As[(tr * 8) * 128];
  const float* Wbase = &Ws[(tc * 8) * 128];
  const int xA = (tr & 3) << 2;
  const int xW = tc << 2;

  #pragma unroll 2
  for (int k4 = 0; k4 < 128; k4 += 4) {
    float4 a[8], wv[8];
    #pragma unroll
    for (int i = 0; i < 8; ++i) a[i] = *(const float4*)&Abase[i * 128 + (k4 ^ xA)];
    #pragma unroll
    for (int j = 0; j < 8; ++j) wv[j] = *(const float4*)&Wbase[j * 128 + (k4 ^ xW)];
    #pragma unroll
    for (int i = 0; i < 8; ++i)
      #pragma unroll
      for (int j = 0; j < 8; ++j)
        acc[i][j] += a[i].x * wv[j].x + a[i].y * wv[j].y + a[i].z * wv[j].z + a[i].w * wv[j].w;
  }

  float bv[8];
  #pragma unroll
  for (int j = 0; j < 8; ++j) bv[j] = bias[tc * 8 + j];

  #pragma unroll
  for (int i = 0; i < 8; ++i) {
    int gr = rowBase + tr * 8 + i;
    if (gr < n) {
      float4 o0, o1;
      o0.x = fmaxf(acc[i][0] + bv[0], 0.f);
      o0.y = fmaxf(acc[i][1] + bv[1], 0.f);
      o0.z = fmaxf(acc[i][2] + bv[2], 0.f);
      o0.w = fmaxf(acc[i][3] + bv[3], 0.f);
      o1.x = fmaxf(acc[i][4] + bv[4], 0.f);
      o1.y = fmaxf(acc[i][5] + bv[5], 0.f);
      o1.z = fmaxf(acc[i][6] + bv[6], 0.f);
      o1.w = fmaxf(acc[i][7] + bv[7], 0.f);
      *(float4*)(out + (size_t)gr * HDIM + tc * 8) = o0;
      *(float4*)(out + (size_t)gr * HDIM + tc * 8 + 4) = o1;
    }
  }
}

// ---------------- final projection: out[i] = dot(h[i], w_out) + b_out ----------------

__global__ void proj_kernel(const float* __restrict__ h, const float* __restrict__ w,
                            const float* __restrict__ b, float* __restrict__ out, int n) {
  int wid = (int)((blockIdx.x * blockDim.x + threadIdx.x) >> 6);
  int lane = threadIdx.x & 63;
  if (wid >= n) return;
  float2 a = *(const float2*)(h + (size_t)wid * HDIM + lane * 2);
  float2 wv = *(const float2*)(w + lane * 2);
  float s = a.x * wv.x + a.y * wv.y;
  #pragma unroll
  for (int off = 32; off > 0; off >>= 1) s += __shfl_down(s, off);
  if (lane == 0) out[wid] = s + b[0];
}

// ---------------- launch ----------------

extern "C" void kernel_launch(void* const* d_in, const int* in_sizes, int n_in,
                              void* d_out, int out_size, void* d_ws, size_t ws_size,
                              hipStream_t stream) {
  const float* x = (const float*)d_in[0];
  const int* ei = (const int*)d_in[1];
  const float* w1[3] = {(const float*)d_in[2], (const float*)d_in[6], (const float*)d_in[10]};
  const float* b1[3] = {(const float*)d_in[3], (const float*)d_in[7], (const float*)d_in[11]};
  const float* w2[3] = {(const float*)d_in[4], (const float*)d_in[8], (const float*)d_in[12]};
  const float* b2[3] = {(const float*)d_in[5], (const float*)d_in[9], (const float*)d_in[13]};
  const float* wout = (const float*)d_in[14];
  const float* bout = (const float*)d_in[15];
  float* out = (float*)d_out;

  char* ws = (char*)d_ws;
  size_t off = 0;
  float* B0 = (float*)(ws + off); off += (size_t)N_NODES * HDIM * 4;
  float* B1 = (float*)(ws + off); off += (size_t)N_NODES * HDIM * 4;
  float* B2 = (float*)(ws + off); off += (size_t)N_NODES * HDIM * 4;
  int* offs   = (int*)(ws + off); off += (size_t)N_NODES * 4;
  int* counts = (int*)(ws + off); off += (size_t)N_NODES * 4;
  int* bsums  = (int*)(ws + off); off += 1024;
  int* srcs   = (int*)(ws + off); off += (size_t)N_EDGES * 4;

  // ---- CSR build (reused by all 3 layers) ----
  hipMemsetAsync(counts, 0, (size_t)N_NODES * 4, stream);
  hist_kernel<<<(N_EDGES + 255) / 256, 256, 0, stream>>>(ei, counts, N_EDGES);
  int nb = (N_NODES + 1023) / 1024;  // 98
  scan1_kernel<<<nb, 256, 0, stream>>>(counts, offs, bsums, N_NODES);
  scan2_kernel<<<1, 128, 0, stream>>>(bsums, nb);
  scan3_kernel<<<(N_NODES + 255) / 256, 256, 0, stream>>>(offs, bsums, N_NODES);
  hipMemsetAsync(counts, 0, (size_t)N_NODES * 4, stream);
  fill_kernel<<<(N_EDGES + 255) / 256, 256, 0, stream>>>(ei, offs, counts, srcs, N_EDGES);

  int aggGrid = (N_NODES * 64 + 255) / 256;   // one wave per node
  int gemmGrid = (N_NODES + 127) / 128;

  // layer 1
  aggregate_kernel<<<aggGrid, 256, 0, stream>>>(x, offs, counts, srcs, B0, N_NODES);
  gemm_kernel<<<gemmGrid, 256, 0, stream>>>(B0, w1[0], b1[0], B1, N_NODES);
  gemm_kernel<<<gemmGrid, 256, 0, stream>>>(B1, w2[0], b2[0], B0, N_NODES);
  // layer 2
  aggregate_kernel<<<aggGrid, 256, 0, stream>>>(B0, offs, counts, srcs, B1, N_NODES);
  gemm_kernel<<<gemmGrid, 256, 0, stream>>>(B1, w1[1], b1[1], B2, N_NODES);
  gemm_kernel<<<gemmGrid, 256, 0, stream>>>(B2, w2[1], b2[1], B1, N_NODES);
  // layer 3
  aggregate_kernel<<<aggGrid, 256, 0, stream>>>(B1, offs, counts, srcs, B2, N_NODES);
  gemm_kernel<<<gemmGrid, 256, 0, stream>>>(B2, w1[2], b1[2], B0, N_NODES);
  gemm_kernel<<<gemmGrid, 256, 0, stream>>>(B0, w2[2], b2[2], B2, N_NODES);
  // output projection
  proj_kernel<<<aggGrid, 256, 0, stream>>>(B2, wout, bout, out, N_NODES);
}